// Round 16
// baseline (272.499 us; speedup 1.0000x reference)
//
#include <hip/hip_runtime.h>

#define N_NODESC 50000
#define N_EDGESC 800000
#define DIMC 128
#define NGC 64
#define HDC 32
#define SLOPEF 0.01f
#define EPSF 1e-5f
#define SCALEF 0.17677669529663687f  // 32^-0.5

#define NBUK 782   // ceil(50000/64) buckets of 64 dst nodes
#define KBLK 50    // binning blocks per side
#define EPB 16000  // edges per binning block (50*16000 = 800000)
#define GG 782     // gemm/pool blocks per side (64 rows each)
#define AG 12500   // agg blocks per side (4 nodes each)

typedef __attribute__((ext_vector_type(8))) short bf16x8;
typedef __attribute__((ext_vector_type(4))) float f32x4;

// fp32 <-> bf16 (RNE)
static __device__ __forceinline__ unsigned short f2bf(float f) {
  unsigned u = __float_as_uint(f);
  u = u + 0x7FFFu + ((u >> 16) & 1u);
  return (unsigned short)(u >> 16);
}
static __device__ __forceinline__ float bf2f(unsigned short h) {
  return __uint_as_float(((unsigned)h) << 16);
}

// ---- int8 pack (RNE + clamp) ----
static __device__ __forceinline__ unsigned pk_i8x4(float a, float b, float c, float d) {
  int q0 = (int)rintf(a); q0 = min(127, max(-127, q0));
  int q1 = (int)rintf(b); q1 = min(127, max(-127, q1));
  int q2 = (int)rintf(c); q2 = min(127, max(-127, q2));
  int q3 = (int)rintf(d); q3 = min(127, max(-127, q3));
  return (unsigned)(q0 & 0xFF) | ((unsigned)(q1 & 0xFF) << 8) |
         ((unsigned)(q2 & 0xFF) << 16) | ((unsigned)(q3 & 0xFF) << 24);
}
// biased-field accumulate of one u32 (4 bytes) into 2 field-accs (even bytes, odd bytes)
static __device__ __forceinline__ void addw_bias(unsigned& a0, unsigned& a1, unsigned w) {
  unsigned b = w ^ 0x80808080u;
  a0 += b & 0x00FF00FFu;
  a1 += (b >> 8) & 0x00FF00FFu;
}

// ---------------- CSR build (both sides per launch) ----------------
__global__ __launch_bounds__(1024) void kbhist2(const int* __restrict__ eiA, const int* __restrict__ eiB,
                                                int* __restrict__ hist) {
  __shared__ int lh[NBUK];
  int side = blockIdx.x / KBLK, blk = blockIdx.x % KBLK;
  const int* ei = side ? eiB : eiA;
  int* hout = hist + side * KBLK * NBUK;
  int t = threadIdx.x;
  for (int i = t; i < NBUK; i += 1024) lh[i] = 0;
  __syncthreads();
  int e0 = blk * EPB;
  for (int e = e0 + t; e < e0 + EPB; e += 1024) {
    int d = ei[N_EDGESC + e];
    atomicAdd(&lh[d >> 6], 1);
  }
  __syncthreads();
  for (int i = t; i < NBUK; i += 1024) hout[blk * NBUK + i] = lh[i];
}

__global__ __launch_bounds__(1024) void kbscan2(const int* __restrict__ hist, int* __restrict__ bbase,
                                                int* __restrict__ bucket_base) {
  __shared__ int sd[1024];
  int side = blockIdx.x;
  const int* h = hist + side * KBLK * NBUK;
  int* bb = bbase + side * KBLK * NBUK;
  int* bub = bucket_base + side * (NBUK + 1);
  int t = threadIdx.x;
  int tot = 0;
  if (t < NBUK) {
    for (int k = 0; k < KBLK; ++k) tot += h[k * NBUK + t];
  }
  sd[t] = tot;
  __syncthreads();
  for (int off = 1; off < 1024; off <<= 1) {
    int u = (t >= off) ? sd[t - off] : 0;
    __syncthreads();
    sd[t] += u;
    __syncthreads();
  }
  if (t < NBUK) {
    int run = sd[t] - tot;  // exclusive bucket base
    bub[t] = run;
    for (int k = 0; k < KBLK; ++k) {
      bb[k * NBUK + t] = run;
      run += h[k * NBUK + t];
    }
  }
  if (t == 0) bub[NBUK] = N_EDGESC;
}

__global__ __launch_bounds__(1024) void kbin2(const int* __restrict__ eiA, const int* __restrict__ eiB,
                                              const int* __restrict__ bbase, unsigned* __restrict__ packed) {
  __shared__ int cur[NBUK];
  int side = blockIdx.x / KBLK, blk = blockIdx.x % KBLK;
  const int* ei = side ? eiB : eiA;
  const int* bb = bbase + side * KBLK * NBUK;
  unsigned* pk = packed + (size_t)side * N_EDGESC;
  int t = threadIdx.x;
  for (int i = t; i < NBUK; i += 1024) cur[i] = bb[blk * NBUK + i];
  __syncthreads();
  int e0 = blk * EPB;
  for (int e = e0 + t; e < e0 + EPB; e += 1024) {
    int s = ei[e];
    int d = ei[N_EDGESC + e];
    int b = d >> 6;
    int pos = atomicAdd(&cur[b], 1);
    pk[pos] = (unsigned)s | ((unsigned)(d & 63) << 16);
  }
}

__global__ __launch_bounds__(256) void kcsr2(const unsigned* __restrict__ packed, const int* __restrict__ bucket_base,
                                             unsigned short* __restrict__ csr16, int* __restrict__ rowptr,
                                             float* __restrict__ inv) {
  __shared__ int h64[64], o64[64], c64[64];
  int side = blockIdx.x / NBUK, b = blockIdx.x % NBUK;
  const unsigned* pk = packed + (size_t)side * N_EDGESC;
  const int* bub = bucket_base + side * (NBUK + 1);
  unsigned short* cs = csr16 + (size_t)side * N_EDGESC;
  int* rp = rowptr + side * (N_NODESC + 1);
  float* iv = inv + side * N_NODESC;
  int t = threadIdx.x;
  int beg = bub[b], end = bub[b + 1];
  if (t < 64) h64[t] = 0;
  __syncthreads();
  for (int e = beg + t; e < end; e += 256) atomicAdd(&h64[pk[e] >> 16], 1);
  __syncthreads();
  if (t == 0) {
    int run = 0;
    for (int j = 0; j < 64; ++j) { o64[j] = run; run += h64[j]; }
  }
  __syncthreads();
  if (t < 64) c64[t] = o64[t];
  __syncthreads();
  for (int e = beg + t; e < end; e += 256) {
    unsigned p = pk[e];
    int pos = atomicAdd(&c64[p >> 16], 1);
    cs[beg + pos] = (unsigned short)(p & 0xFFFFu);
  }
  if (t < 64) {
    int node = b * 64 + t;
    if (node < N_NODESC) {
      rp[node] = beg + o64[t];
      iv[node] = rsqrtf((float)h64[t] + 1.0f);
    }
  }
  if (b == NBUK - 1 && t == 0) rp[N_NODESC] = N_EDGESC;
}

// ---------------- W pre-transform: fragment-major hi/lo bf16 ----------------
__global__ __launch_bounds__(256) void wconv(const float* __restrict__ W0, const float* __restrict__ W1,
                                             const float* __restrict__ W2, const float* __restrict__ W3,
                                             unsigned short* __restrict__ Wt) {
  int m = blockIdx.x >> 4;                              // matrix 0..3
  int idx = (blockIdx.x & 15) * 256 + threadIdx.x;      // 0..4095: (fs,lane)
  int fs = idx >> 6, lane = idx & 63;
  int ks = fs >> 3, nf = fs & 7;
  int n = nf * 16 + (lane & 15);
  int k0 = ks * 32 + (lane >> 4) * 8;
  const float* W = (m == 0) ? W0 : (m == 1) ? W1 : (m == 2) ? W2 : W3;
  unsigned short* hi = Wt + (size_t)m * 128 * 512 + (size_t)(fs * 2) * 512 + lane * 8;
  bf16x8 vh, vl;
#pragma unroll
  for (int j = 0; j < 8; ++j) {
    float a = W[(k0 + j) * DIMC + n];
    unsigned short h = f2bf(a);
    vh[j] = (short)h;
    vl[j] = (short)f2bf(a - bf2f(h));
  }
  *(bf16x8*)hi = vh;
  *(bf16x8*)(hi + 512) = vl;
}

// Shared epilogue: scaled (x16) bf16 in LDS -> int8 rows (32 uints/row).
static __device__ __forceinline__ void epi_store_i8(const unsigned short* lds, unsigned* Y, int lb) {
  int tr = threadIdx.x >> 2, q = threadIdx.x & 3;
  int grow = lb * 64 + tr;
  if (grow >= N_NODESC) return;
#pragma unroll
  for (int i = 0; i < 8; ++i) {
    int col = (q + 4 * i) * 4;
    ushort4 v = *(const ushort4*)&lds[tr * 136 + col];
    unsigned pk = pk_i8x4(bf2f(v.x), bf2f(v.y), bf2f(v.z), bf2f(v.w));
    Y[(size_t)grow * 32 + q + 4 * i] = pk;
  }
}

// ---------------- GEMM layer1 (fp32 in): h(int8, x16) = (X @ W1) * inv * 16 ----------------
__global__ __launch_bounds__(256) void gemm_l1(const float* __restrict__ xA, const float* __restrict__ xB,
                                               const unsigned short* __restrict__ Wt, const float* __restrict__ inv,
                                               unsigned* __restrict__ H) {
  __shared__ unsigned short lds[64 * 136];
  int side = blockIdx.x / GG, lb = blockIdx.x % GG;
  const float* X = side ? xB : xA;
  const unsigned short* Wm = Wt + (size_t)(side * 2) * 128 * 512;
  const float* iv = inv + side * N_NODESC;
  unsigned* Y = H + (size_t)side * N_NODESC * 32;
  int wave = threadIdx.x >> 6, lane = threadIdx.x & 63;
  int l15 = lane & 15, kb = lane >> 4;
  int row0 = lb * 64 + wave * 16;
  int rA = row0 + l15;
  const bool valid = rA < N_NODESC;
  f32x4 acc[8];
#pragma unroll
  for (int nf = 0; nf < 8; ++nf) acc[nf] = 0.f;
#pragma unroll
  for (int ks = 0; ks < 4; ++ks) {
    int kbase = ks * 32 + kb * 8;
    bf16x8 a;
    if (valid) {
      const float* xp = &X[(size_t)rA * DIMC + kbase];
      float4 x0 = *(const float4*)xp;
      float4 x1 = *(const float4*)(xp + 4);
      a[0] = (short)f2bf(x0.x); a[1] = (short)f2bf(x0.y);
      a[2] = (short)f2bf(x0.z); a[3] = (short)f2bf(x0.w);
      a[4] = (short)f2bf(x1.x); a[5] = (short)f2bf(x1.y);
      a[6] = (short)f2bf(x1.z); a[7] = (short)f2bf(x1.w);
    } else {
      a = (short)0;
    }
    const unsigned short* wp = Wm + (size_t)(ks * 16) * 512 + lane * 8;
#pragma unroll
    for (int nf = 0; nf < 8; ++nf) {
      bf16x8 bh = *(const bf16x8*)(wp + (nf * 2) * 512);
      bf16x8 bl = *(const bf16x8*)(wp + (nf * 2 + 1) * 512);
      acc[nf] = __builtin_amdgcn_mfma_f32_16x16x32_bf16(a, bh, acc[nf], 0, 0, 0);
      acc[nf] = __builtin_amdgcn_mfma_f32_16x16x32_bf16(a, bl, acc[nf], 0, 0, 0);
    }
  }
  int lrow = wave * 16 + kb * 4;
#pragma unroll
  for (int r = 0; r < 4; ++r) {
    int rr = row0 + kb * 4 + r;
    float s = (rr < N_NODESC) ? iv[rr] * 16.0f : 0.f;  // x16 into int8 range
#pragma unroll
    for (int nf = 0; nf < 8; ++nf) {
      lds[(lrow + r) * 136 + nf * 16 + l15] = f2bf(acc[nf][r] * s);
    }
  }
  __syncthreads();
  epi_store_i8(lds, Y, lb);
}

// ---------------- GEMM layer2 (bf16 in): h(int8, x16) = (G @ W2) * inv * 16 ----------------
__global__ __launch_bounds__(256) void gemm_l2(const unsigned short* __restrict__ Gb,
                                               const unsigned short* __restrict__ Wt, const float* __restrict__ inv,
                                               unsigned* __restrict__ H) {
  __shared__ unsigned short lds[64 * 136];
  int side = blockIdx.x / GG, lb = blockIdx.x % GG;
  const unsigned short* X = Gb + (size_t)side * N_NODESC * DIMC;
  const unsigned short* Wm = Wt + (size_t)(side * 2 + 1) * 128 * 512;
  const float* iv = inv + side * N_NODESC;
  unsigned* Y = H + (size_t)side * N_NODESC * 32;
  int wave = threadIdx.x >> 6, lane = threadIdx.x & 63;
  int l15 = lane & 15, kb = lane >> 4;
  int row0 = lb * 64 + wave * 16;
  int rA = row0 + l15;
  const bool valid = rA < N_NODESC;
  f32x4 acc[8];
#pragma unroll
  for (int nf = 0; nf < 8; ++nf) acc[nf] = 0.f;
#pragma unroll
  for (int ks = 0; ks < 4; ++ks) {
    int kbase = ks * 32 + kb * 8;
    bf16x8 a;
    if (valid) {
      a = *(const bf16x8*)&X[(size_t)rA * DIMC + kbase];
    } else {
      a = (short)0;
    }
    const unsigned short* wp = Wm + (size_t)(ks * 16) * 512 + lane * 8;
#pragma unroll
    for (int nf = 0; nf < 8; ++nf) {
      bf16x8 bh = *(const bf16x8*)(wp + (nf * 2) * 512);
      bf16x8 bl = *(const bf16x8*)(wp + (nf * 2 + 1) * 512);
      acc[nf] = __builtin_amdgcn_mfma_f32_16x16x32_bf16(a, bh, acc[nf], 0, 0, 0);
      acc[nf] = __builtin_amdgcn_mfma_f32_16x16x32_bf16(a, bl, acc[nf], 0, 0, 0);
    }
  }
  int lrow = wave * 16 + kb * 4;
#pragma unroll
  for (int r = 0; r < 4; ++r) {
    int rr = row0 + kb * 4 + r;
    float s = (rr < N_NODESC) ? iv[rr] * 16.0f : 0.f;
#pragma unroll
    for (int nf = 0; nf < 8; ++nf) {
      lds[(lrow + r) * 136 + nf * 16 + l15] = f2bf(acc[nf][r] * s);
    }
  }
  __syncthreads();
  epi_store_i8(lds, Y, lb);
}

// ---------------- aggregation: 16B/lane, 8 lanes/row, 8 edge-slots/wave ----------------
// Wave = 1 node. lane = slot*8 + d8; d8 covers dims 16*d8..16*d8+15 (16B).
// 8 edges per uint4 gather instruction; 32-bit voffset addressing.
__global__ __launch_bounds__(256) void agg12(const unsigned* __restrict__ H, const float* __restrict__ inv,
                                             const int* __restrict__ rowptr, const unsigned short* __restrict__ csr16,
                                             const float* __restrict__ biasA, const float* __restrict__ biasB,
                                             unsigned short* __restrict__ G, int do_relu) {
  int side = blockIdx.x / AG, lb = blockIdx.x % AG;
  int node = lb * 4 + (threadIdx.x >> 6);
  if (node >= N_NODESC) return;
  const unsigned char* Hp = (const unsigned char*)(H + (size_t)side * N_NODESC * 32);
  const float* iv = inv + side * N_NODESC;
  const int* rp = rowptr + side * (N_NODESC + 1);
  const unsigned short* csr = csr16 + (size_t)side * N_EDGESC;
  const float* bias = side ? biasB : biasA;
  unsigned short* out = G + (size_t)side * N_NODESC * DIMC;
  int lane = threadIdx.x & 63;
  int d8 = lane & 7;     // dim block: 16 dims (16B)
  int slot = lane >> 3;  // 0..7 edge slots
  unsigned boff = (unsigned)d8 << 4;
  int beg = rp[node], end = rp[node + 1];
  unsigned acc[8];
#pragma unroll
  for (int j = 0; j < 8; ++j) acc[j] = 0u;
  for (int e = beg + slot; e < end; e += 8) {
    unsigned s = csr[e];
    uint4 u = *(const uint4*)(Hp + ((s << 7) | boff));
    addw_bias(acc[0], acc[1], u.x);
    addw_bias(acc[2], acc[3], u.y);
    addw_bias(acc[4], acc[5], u.z);
    addw_bias(acc[6], acc[7], u.w);
  }
#pragma unroll
  for (int j = 0; j < 8; ++j) {
    acc[j] += __shfl_xor(acc[j], 8, 64);
    acc[j] += __shfl_xor(acc[j], 16, 64);
    acc[j] += __shfl_xor(acc[j], 32, 64);
  }
  if (slot == 0) {
    uint4 su = *(const uint4*)(Hp + (((unsigned)node << 7) | boff));
    addw_bias(acc[0], acc[1], su.x);
    addw_bias(acc[2], acc[3], su.y);
    addw_bias(acc[4], acc[5], su.z);
    addw_bias(acc[6], acc[7], su.w);
    int cnt = (end - beg) + 1;
    int bs = cnt << 7;  // 128 * cnt
    float sc = iv[node] * 0.0625f;  // undo x16
    int dbase = d8 * 16;
    // acc[2p]:(dims 4p+0, 4p+2), acc[2p+1]:(dims 4p+1, 4p+3) within the 16-dim block
    float o[16];
#pragma unroll
    for (int p = 0; p < 4; ++p) {
      o[4 * p + 0] = (float)((int)(acc[2 * p] & 0xFFFFu) - bs);
      o[4 * p + 1] = (float)((int)(acc[2 * p + 1] & 0xFFFFu) - bs);
      o[4 * p + 2] = (float)((int)(acc[2 * p] >> 16) - bs);
      o[4 * p + 3] = (float)((int)(acc[2 * p + 1] >> 16) - bs);
    }
#pragma unroll
    for (int j = 0; j < 16; ++j) {
      float v = o[j] * sc + bias[dbase + j];
      if (do_relu) v = (v > 0.f) ? v : SLOPEF * v;
      o[j] = v;
    }
    uint4 w0, w1;
    w0.x = (unsigned)f2bf(o[0]) | ((unsigned)f2bf(o[1]) << 16);
    w0.y = (unsigned)f2bf(o[2]) | ((unsigned)f2bf(o[3]) << 16);
    w0.z = (unsigned)f2bf(o[4]) | ((unsigned)f2bf(o[5]) << 16);
    w0.w = (unsigned)f2bf(o[6]) | ((unsigned)f2bf(o[7]) << 16);
    w1.x = (unsigned)f2bf(o[8]) | ((unsigned)f2bf(o[9]) << 16);
    w1.y = (unsigned)f2bf(o[10]) | ((unsigned)f2bf(o[11]) << 16);
    w1.z = (unsigned)f2bf(o[12]) | ((unsigned)f2bf(o[13]) << 16);
    w1.w = (unsigned)f2bf(o[14]) | ((unsigned)f2bf(o[15]) << 16);
    *(uint4*)&out[(size_t)node * DIMC + dbase] = w0;
    *(uint4*)&out[(size_t)node * DIMC + dbase + 8] = w1;
  }
}

// ---------------- pooling (both sides, bf16 in) ----------------
__global__ __launch_bounds__(128) void pool2(const unsigned short* __restrict__ G,
                                             const int* __restrict__ batA, const int* __restrict__ batB,
                                             float* __restrict__ psA, float* __restrict__ psB,
                                             int* __restrict__ pcA, int* __restrict__ pcB) {
  int side = blockIdx.x / GG, lb = blockIdx.x % GG;
  const unsigned short* g = G + (size_t)side * N_NODESC * DIMC;
  const int* batch = side ? batB : batA;
  float* psum = side ? psB : psA;
  int* pcnt = side ? pcB : pcA;
  int t = threadIdx.x;
  int n0 = lb * 64;
  int nend = min(n0 + 64, N_NODESC);
  int cur = batch[n0];
  float acc = 0.f;
  int c = 0;
  for (int n = n0; n < nend; ++n) {
    int b = batch[n];
    if (b != cur) {
      atomicAdd(&psum[cur * DIMC + t], acc);
      if (t == 0) atomicAdd(&pcnt[cur], c);
      acc = 0.f;
      c = 0;
      cur = b;
    }
    acc += bf2f(g[(size_t)n * DIMC + t]);
    c += 1;
  }
  atomicAdd(&psum[cur * DIMC + t], acc);
  if (t == 0) atomicAdd(&pcnt[cur], c);
}

// ---------------- fused mean + qkv ----------------
__global__ __launch_bounds__(128) void meanqkv(const float* __restrict__ psA, const int* __restrict__ pcA,
                                               const float* __restrict__ psB, const int* __restrict__ pcB,
                                               const float* __restrict__ Wq, const float* __restrict__ bq,
                                               const float* __restrict__ Wk, const float* __restrict__ bk,
                                               const float* __restrict__ Wv, const float* __restrict__ bv,
                                               float* __restrict__ mhA, float* __restrict__ mhB,
                                               float* __restrict__ Q0, float* __restrict__ K0, float* __restrict__ V0,
                                               float* __restrict__ Q1, float* __restrict__ K1, float* __restrict__ V1) {
  __shared__ float xs[DIMC];
  int task = blockIdx.x >> 6, r = blockIdx.x & 63, t = threadIdx.x;
  bool sideA = (task == 0 || task == 4 || task == 5);
  const float* ps = sideA ? psA : psB;
  const int* pc = sideA ? pcA : pcB;
  const float *W, *b;
  float* Y;
  switch (task) {
    case 0: W = Wq; b = bq; Y = Q0; break;
    case 1: W = Wk; b = bk; Y = K0; break;
    case 2: W = Wv; b = bv; Y = V0; break;
    case 3: W = Wq; b = bq; Y = Q1; break;
    case 4: W = Wk; b = bk; Y = K1; break;
    default: W = Wv; b = bv; Y = V1; break;
  }
  float xv = ps[r * DIMC + t] / (float)max(pc[r], 1);
  xs[t] = xv;
  if (task == 0) mhA[r * DIMC + t] = xv;
  if (task == 3) mhB[r * DIMC + t] = xv;
  __syncthreads();
  float acc = b[t];
  for (int k = 0; k < DIMC; ++k) acc += xs[k] * W[k * DIMC + t];
  Y[r * DIMC + t] = acc;
}

__global__ __launch_bounds__(64) void attn_kernel(const float* __restrict__ Q0, const float* __restrict__ K0,
                                                  const float* __restrict__ V0, const float* __restrict__ Q1,
                                                  const float* __restrict__ K1, const float* __restrict__ V1,
                                                  float* __restrict__ O0, float* __restrict__ O1) {
  __shared__ float ps[64];
  int b = blockIdx.x;
  int dir = b >> 8, h = (b >> 6) & 3, q = b & 63;
  const float* Q = dir ? Q1 : Q0;
  const float* K = dir ? K1 : K0;
  const float* V = dir ? V1 : V0;
  float* O = dir ? O1 : O0;
  int k = threadIdx.x;
  const float* qp = Q + q * DIMC + h * HDC;
  const float* kp = K + k * DIMC + h * HDC;
  float s = 0.f;
#pragma unroll
  for (int d = 0; d < HDC; ++d) s += qp[d] * kp[d];
  s *= SCALEF;
  float m = s;
#pragma unroll
  for (int off = 32; off >= 1; off >>= 1) m = fmaxf(m, __shfl_xor(m, off, 64));
  float p = __expf(s - m);
  float sum = p;
#pragma unroll
  for (int off = 32; off >= 1; off >>= 1) sum += __shfl_xor(sum, off, 64);
  p /= sum;
  ps[k] = p;
  __syncthreads();
  int half = k >> 5, d = k & 31;
  float acc = 0.f;
#pragma unroll
  for (int j = 0; j < 32; ++j) {
    int kk = half * 32 + j;
    acc += ps[kk] * V[kk * DIMC + h * HDC + d];
  }
  acc += __shfl_xor(acc, 32, 64);
  if (half == 0) O[q * DIMC + h * HDC + d] = acc;
}

__device__ inline float blk_sum128(float v, float* red) {
#pragma unroll
  for (int off = 32; off >= 1; off >>= 1) v += __shfl_xor(v, off, 64);
  if ((threadIdx.x & 63) == 0) red[threadIdx.x >> 6] = v;
  __syncthreads();
  float r = red[0] + red[1];
  __syncthreads();
  return r;
}

// ---------------- fused oln + ff1 (256 thr: LN on t<128, FF1 on all) ----------------
__global__ __launch_bounds__(256) void olnff1(const float* __restrict__ O0, const float* __restrict__ O1,
                                              const float* __restrict__ mhA, const float* __restrict__ mhB,
                                              const float* __restrict__ Wo, const float* __restrict__ bo,
                                              const float* __restrict__ g1, const float* __restrict__ be1,
                                              const float* __restrict__ Wf1, const float* __restrict__ bf1,
                                              float* __restrict__ X0, float* __restrict__ X1,
                                              float* __restrict__ F0, float* __restrict__ F1) {
  __shared__ float os[DIMC];
  __shared__ float xs[DIMC];
  __shared__ float red4[4];
  int dir = blockIdx.x >> 6, q = blockIdx.x & 63, t = threadIdx.x;
  const float* O = dir ? O1 : O0;
  const float* xq = dir ? mhB : mhA;
  float* Xo = dir ? X1 : X0;
  float* F = dir ? F1 : F0;
  if (t < DIMC) os[t] = O[q * DIMC + t];
  __syncthreads();
  bool act = t < DIMC;
  float acc = 0.f;
  if (act) {
    acc = bo[t] + xq[q * DIMC + t];
    for (int k = 0; k < DIMC; ++k) acc += os[k] * Wo[k * DIMC + t];
  }
  float v = act ? acc : 0.f;
#pragma unroll
  for (int off = 32; off >= 1; off >>= 1) v += __shfl_xor(v, off, 64);
  if ((t & 63) == 0) red4[t >> 6] = v;
  __syncthreads();
  float mean = (red4[0] + red4[1] + red4[2] + red4[3]) * (1.f / DIMC);
  __syncthreads();
  float d = act ? (acc - mean) : 0.f;
  float v2 = d * d;
#pragma unroll
  for (int off = 32; off >= 1; off >>= 1) v2 += __shfl_xor(v2, off, 64);
  if ((t & 63) == 0) red4[t >> 6] = v2;
  __syncthreads();
  float var = (red4[0] + red4[1] + red4[2] + red4[3]) * (1.f / DIMC);
  if (act) {
    float xv = d * rsqrtf(var + EPSF) * g1[t] + be1[t];
    xs[t] = xv;
    Xo[q * DIMC + t] = xv;
  }
  __syncthreads();
  float facc = bf1[t];
  for (int k = 0; k < DIMC; ++k) facc += xs[k] * Wf1[k * 256 + t];
  facc = (facc > 0.f) ? facc : SLOPEF * facc;
  F[q * 256 + t] = facc;
}

// ---------------- fused ffln (both dirs) + head ----------------
__global__ __launch_bounds__(128) void fflnhead(const float* __restrict__ F0, const float* __restrict__ F1,
                                                const float* __restrict__ X0, const float* __restrict__ X1,
                                                const float* __restrict__ Wf2, const float* __restrict__ bf2,
                                                const float* __restrict__ g2, const float* __restrict__ be2,
                                                const float* __restrict__ Wl1, const float* __restrict__ bl1,
                                                const float* __restrict__ Wl2, const float* __restrict__ bl2,
                                                float* __restrict__ out) {
  __shared__ float fs[256];
  __shared__ float cs[256];
  __shared__ float red[2];
  int g = blockIdx.x, t = threadIdx.x;
  for (int dir = 0; dir < 2; ++dir) {
    const float* F = dir ? F1 : F0;
    const float* X = dir ? X1 : X0;
    fs[t] = F[g * 256 + t];
    fs[t + 128] = F[g * 256 + t + 128];
    __syncthreads();
    float acc = bf2[t] + X[g * DIMC + t];
    for (int k = 0; k < 256; ++k) acc += fs[k] * Wf2[k * DIMC + t];
    float mean = blk_sum128(acc, red) * (1.f / DIMC);
    float d = acc - mean;
    float var = blk_sum128(d * d, red) * (1.f / DIMC);
    cs[dir * DIMC + t] = d * rsqrtf(var + EPSF) * g2[t] + be2[t];
    __syncthreads();
  }
  float acc = bl1[t];
  for (int k = 0; k < 256; ++k) acc += cs[k] * Wl1[k * DIMC + t];
  acc = fmaxf(acc, 0.f);
  float s = blk_sum128(acc * Wl2[t], red);
  if (t == 0) out[g] = s + bl2[0];
}

// ---------------- host ----------------
extern "C" void kernel_launch(void* const* d_in, const int* in_sizes, int n_in,
                              void* d_out, int out_size, void* d_ws, size_t ws_size,
                              hipStream_t stream) {
  const float* xA = (const float*)d_in[0];
  const float* xB = (const float*)d_in[1];
  const int* eiA = (const int*)d_in[2];
  const int* eiB = (const int*)d_in[3];
  const int* batA = (const int*)d_in[4];
  const int* batB = (const int*)d_in[5];
  const float* WA1 = (const float*)d_in[6];
  const float* WA2 = (const float*)d_in[7];
  const float* WB1 = (const float*)d_in[8];
  const float* WB2 = (const float*)d_in[9];
  const float* Wq = (const float*)d_in[10];
  const float* Wk = (const float*)d_in[11];
  const float* Wv = (const float*)d_in[12];
  const float* Wo = (const float*)d_in[13];
  const float* Wf1 = (const float*)d_in[14];
  const float* Wf2 = (const float*)d_in[15];
  const float* Wl1 = (const float*)d_in[16];
  const float* Wl2 = (const float*)d_in[17];
  const float* bA1 = (const float*)d_in[18];
  const float* bA2 = (const float*)d_in[19];
  const float* bB1 = (const float*)d_in[20];
  const float* bB2 = (const float*)d_in[21];
  const float* bq = (const float*)d_in[22];
  const float* bk = (const float*)d_in[23];
  const float* bv = (const float*)d_in[24];
  const float* bo = (const float*)d_in[25];
  const float* bf1 = (const float*)d_in[26];
  const float* bf2 = (const float*)d_in[27];
  const float* bl1 = (const float*)d_in[28];
  const float* bl2 = (const float*)d_in[29];
  const float* g1 = (const float*)d_in[30];
  const float* be1 = (const float*)d_in[31];
  const float* g2 = (const float*)d_in[32];
  const float* be2 = (const float*)d_in[33];

  char* base = (char*)d_ws;
  size_t off = 0;
  auto alloc = [&](size_t bytes) -> char* {
    char* r = base + off;
    off += (bytes + 255) & ~(size_t)255;
    return r;
  };
  unsigned* h_buf = (unsigned*)alloc((size_t)2 * N_NODESC * 32 * 4);                // int8 x16, both sides
  unsigned short* g_buf = (unsigned short*)alloc((size_t)2 * N_NODESC * DIMC * 2);  // bf16, both sides
  unsigned* packed = (unsigned*)alloc((size_t)2 * N_EDGESC * 4);
  unsigned short* csr16 = (unsigned short*)alloc((size_t)2 * N_EDGESC * 2);
  int* rowptr = (int*)alloc((size_t)2 * (N_NODESC + 1) * 4);
  float* inv = (float*)alloc((size_t)2 * N_NODESC * 4);
  int* hist = (int*)alloc((size_t)2 * KBLK * NBUK * 4);
  int* bbase = (int*)alloc((size_t)2 * KBLK * NBUK * 4);
  int* bucket_base = (int*)alloc((size_t)2 * (NBUK + 1) * 4);
  unsigned short* wtbuf = (unsigned short*)alloc((size_t)4 * 128 * 512 * 2);
  size_t poff0 = off;
  float* psA = (float*)alloc(NGC * DIMC * 4);
  float* psB = (float*)alloc(NGC * DIMC * 4);
  int* pcA = (int*)alloc(NGC * 4);
  int* pcB = (int*)alloc(NGC * 4);
  size_t pbytes = off - poff0;
  float* mhA = (float*)alloc(NGC * DIMC * 4);
  float* mhB = (float*)alloc(NGC * DIMC * 4);
  float* Q0 = (float*)alloc(NGC * DIMC * 4);
  float* K0 = (float*)alloc(NGC * DIMC * 4);
  float* V0 = (float*)alloc(NGC * DIMC * 4);
  float* Q1 = (float*)alloc(NGC * DIMC * 4);
  float* K1 = (float*)alloc(NGC * DIMC * 4);
  float* V1 = (float*)alloc(NGC * DIMC * 4);
  float* O0 = (float*)alloc(NGC * DIMC * 4);
  float* O1 = (float*)alloc(NGC * DIMC * 4);
  float* X0 = (float*)alloc(NGC * DIMC * 4);
  float* X1 = (float*)alloc(NGC * DIMC * 4);
  float* F0 = (float*)alloc(NGC * 256 * 4);
  float* F1 = (float*)alloc(NGC * 256 * 4);

  hipMemsetAsync(base + poff0, 0, pbytes, stream);
  wconv<<<64, 256, 0, stream>>>(WA1, WA2, WB1, WB2, wtbuf);

  kbhist2<<<2 * KBLK, 1024, 0, stream>>>(eiA, eiB, hist);
  kbscan2<<<2, 1024, 0, stream>>>(hist, bbase, bucket_base);
  kbin2<<<2 * KBLK, 1024, 0, stream>>>(eiA, eiB, bbase, packed);
  kcsr2<<<2 * NBUK, 256, 0, stream>>>(packed, bucket_base, csr16, rowptr, inv);

  gemm_l1<<<2 * GG, 256, 0, stream>>>(xA, xB, wtbuf, inv, h_buf);
  agg12<<<2 * AG, 256, 0, stream>>>(h_buf, inv, rowptr, csr16, bA1, bB1, g_buf, 1);
  gemm_l2<<<2 * GG, 256, 0, stream>>>(g_buf, wtbuf, inv, h_buf);
  agg12<<<2 * AG, 256, 0, stream>>>(h_buf, inv, rowptr, csr16, bA2, bB2, g_buf, 0);
  pool2<<<2 * GG, 128, 0, stream>>>(g_buf, batA, batB, psA, psB, pcA, pcB);

  meanqkv<<<384, 128, 0, stream>>>(psA, pcA, psB, pcB, Wq, bq, Wk, bk, Wv, bv,
                                   mhA, mhB, Q0, K0, V0, Q1, K1, V1);
  attn_kernel<<<512, 64, 0, stream>>>(Q0, K0, V0, Q1, K1, V1, O0, O1);
  olnff1<<<128, 256, 0, stream>>>(O0, O1, mhA, mhB, Wo, bo, g1, be1, Wf1, bf1, X0, X1, F0, F1);
  fflnhead<<<64, 128, 0, stream>>>(F0, F1, X0, X1, Wf2, bf2, g2, be2, Wl1, bl1, Wl2, bl2, (float*)d_out);
}

// Round 17
// 263.622 us; speedup vs baseline: 1.0337x; 1.0337x over previous
//
#include <hip/hip_runtime.h>

#define N_NODESC 50000
#define N_EDGESC 800000
#define DIMC 128
#define NGC 64
#define HDC 32
#define SLOPEF 0.01f
#define EPSF 1e-5f
#define SCALEF 0.17677669529663687f  // 32^-0.5

#define NBUK 782   // ceil(50000/64) buckets of 64 dst nodes
#define KBLK 50    // binning blocks per side
#define EPB 16000  // edges per binning block (50*16000 = 800000)
#define GG 782     // gemm/pool blocks per side (64 rows each)
#define AG 12500   // agg blocks per side (4 nodes each)

typedef __attribute__((ext_vector_type(8))) short bf16x8;
typedef __attribute__((ext_vector_type(4))) float f32x4;

// fp32 <-> bf16 (RNE)
static __device__ __forceinline__ unsigned short f2bf(float f) {
  unsigned u = __float_as_uint(f);
  u = u + 0x7FFFu + ((u >> 16) & 1u);
  return (unsigned short)(u >> 16);
}
static __device__ __forceinline__ float bf2f(unsigned short h) {
  return __uint_as_float(((unsigned)h) << 16);
}

// ---- int8 pack (RNE + clamp) ----
static __device__ __forceinline__ unsigned pk_i8x4(float a, float b, float c, float d) {
  int q0 = (int)rintf(a); q0 = min(127, max(-127, q0));
  int q1 = (int)rintf(b); q1 = min(127, max(-127, q1));
  int q2 = (int)rintf(c); q2 = min(127, max(-127, q2));
  int q3 = (int)rintf(d); q3 = min(127, max(-127, q3));
  return (unsigned)(q0 & 0xFF) | ((unsigned)(q1 & 0xFF) << 8) |
         ((unsigned)(q2 & 0xFF) << 16) | ((unsigned)(q3 & 0xFF) << 24);
}
// biased-field accumulate: bytes ^ 0x80 -> unsigned; two bytes per u32 in 16-bit fields.
// acc[0]:(d0,d2) acc[1]:(d1,d3) acc[2]:(d4,d6) acc[3]:(d5,d7). 8 VALU per uint2.
static __device__ __forceinline__ void addu2_bias(unsigned* acc, uint2 u) {
  unsigned bx = u.x ^ 0x80808080u;
  unsigned by = u.y ^ 0x80808080u;
  acc[0] += bx & 0x00FF00FFu;
  acc[1] += (bx >> 8) & 0x00FF00FFu;
  acc[2] += by & 0x00FF00FFu;
  acc[3] += (by >> 8) & 0x00FF00FFu;
}

// ---------------- CSR build (both sides per launch) ----------------
__global__ __launch_bounds__(1024) void kbhist2(const int* __restrict__ eiA, const int* __restrict__ eiB,
                                                int* __restrict__ hist) {
  __shared__ int lh[NBUK];
  int side = blockIdx.x / KBLK, blk = blockIdx.x % KBLK;
  const int* ei = side ? eiB : eiA;
  int* hout = hist + side * KBLK * NBUK;
  int t = threadIdx.x;
  for (int i = t; i < NBUK; i += 1024) lh[i] = 0;
  __syncthreads();
  int e0 = blk * EPB;
  for (int e = e0 + t; e < e0 + EPB; e += 1024) {
    int d = ei[N_EDGESC + e];
    atomicAdd(&lh[d >> 6], 1);
  }
  __syncthreads();
  for (int i = t; i < NBUK; i += 1024) hout[blk * NBUK + i] = lh[i];
}

__global__ __launch_bounds__(1024) void kbscan2(const int* __restrict__ hist, int* __restrict__ bbase,
                                                int* __restrict__ bucket_base) {
  __shared__ int sd[1024];
  int side = blockIdx.x;
  const int* h = hist + side * KBLK * NBUK;
  int* bb = bbase + side * KBLK * NBUK;
  int* bub = bucket_base + side * (NBUK + 1);
  int t = threadIdx.x;
  int tot = 0;
  if (t < NBUK) {
    for (int k = 0; k < KBLK; ++k) tot += h[k * NBUK + t];
  }
  sd[t] = tot;
  __syncthreads();
  for (int off = 1; off < 1024; off <<= 1) {
    int u = (t >= off) ? sd[t - off] : 0;
    __syncthreads();
    sd[t] += u;
    __syncthreads();
  }
  if (t < NBUK) {
    int run = sd[t] - tot;  // exclusive bucket base
    bub[t] = run;
    for (int k = 0; k < KBLK; ++k) {
      bb[k * NBUK + t] = run;
      run += h[k * NBUK + t];
    }
  }
  if (t == 0) bub[NBUK] = N_EDGESC;
}

__global__ __launch_bounds__(1024) void kbin2(const int* __restrict__ eiA, const int* __restrict__ eiB,
                                              const int* __restrict__ bbase, unsigned* __restrict__ packed) {
  __shared__ int cur[NBUK];
  int side = blockIdx.x / KBLK, blk = blockIdx.x % KBLK;
  const int* ei = side ? eiB : eiA;
  const int* bb = bbase + side * KBLK * NBUK;
  unsigned* pk = packed + (size_t)side * N_EDGESC;
  int t = threadIdx.x;
  for (int i = t; i < NBUK; i += 1024) cur[i] = bb[blk * NBUK + i];
  __syncthreads();
  int e0 = blk * EPB;
  for (int e = e0 + t; e < e0 + EPB; e += 1024) {
    int s = ei[e];
    int d = ei[N_EDGESC + e];
    int b = d >> 6;
    int pos = atomicAdd(&cur[b], 1);
    pk[pos] = (unsigned)s | ((unsigned)(d & 63) << 16);
  }
}

__global__ __launch_bounds__(256) void kcsr2(const unsigned* __restrict__ packed, const int* __restrict__ bucket_base,
                                             unsigned short* __restrict__ csr16, int* __restrict__ rowptr,
                                             float* __restrict__ inv) {
  __shared__ int h64[64], o64[64], c64[64];
  int side = blockIdx.x / NBUK, b = blockIdx.x % NBUK;
  const unsigned* pk = packed + (size_t)side * N_EDGESC;
  const int* bub = bucket_base + side * (NBUK + 1);
  unsigned short* cs = csr16 + (size_t)side * N_EDGESC;
  int* rp = rowptr + side * (N_NODESC + 1);
  float* iv = inv + side * N_NODESC;
  int t = threadIdx.x;
  int beg = bub[b], end = bub[b + 1];
  if (t < 64) h64[t] = 0;
  __syncthreads();
  for (int e = beg + t; e < end; e += 256) atomicAdd(&h64[pk[e] >> 16], 1);
  __syncthreads();
  if (t == 0) {
    int run = 0;
    for (int j = 0; j < 64; ++j) { o64[j] = run; run += h64[j]; }
  }
  __syncthreads();
  if (t < 64) c64[t] = o64[t];
  __syncthreads();
  for (int e = beg + t; e < end; e += 256) {
    unsigned p = pk[e];
    int pos = atomicAdd(&c64[p >> 16], 1);
    cs[beg + pos] = (unsigned short)(p & 0xFFFFu);
  }
  if (t < 64) {
    int node = b * 64 + t;
    if (node < N_NODESC) {
      rp[node] = beg + o64[t];
      iv[node] = rsqrtf((float)h64[t] + 1.0f);
    }
  }
  if (b == NBUK - 1 && t == 0) rp[N_NODESC] = N_EDGESC;
}

// ---------------- W pre-transform: fragment-major hi/lo bf16 ----------------
__global__ __launch_bounds__(256) void wconv(const float* __restrict__ W0, const float* __restrict__ W1,
                                             const float* __restrict__ W2, const float* __restrict__ W3,
                                             unsigned short* __restrict__ Wt) {
  int m = blockIdx.x >> 4;                              // matrix 0..3
  int idx = (blockIdx.x & 15) * 256 + threadIdx.x;      // 0..4095: (fs,lane)
  int fs = idx >> 6, lane = idx & 63;
  int ks = fs >> 3, nf = fs & 7;
  int n = nf * 16 + (lane & 15);
  int k0 = ks * 32 + (lane >> 4) * 8;
  const float* W = (m == 0) ? W0 : (m == 1) ? W1 : (m == 2) ? W2 : W3;
  unsigned short* hi = Wt + (size_t)m * 128 * 512 + (size_t)(fs * 2) * 512 + lane * 8;
  bf16x8 vh, vl;
#pragma unroll
  for (int j = 0; j < 8; ++j) {
    float a = W[(k0 + j) * DIMC + n];
    unsigned short h = f2bf(a);
    vh[j] = (short)h;
    vl[j] = (short)f2bf(a - bf2f(h));
  }
  *(bf16x8*)hi = vh;
  *(bf16x8*)(hi + 512) = vl;
}

// Shared epilogue: scaled (x16) bf16 in LDS -> int8 rows (32 uints/row).
static __device__ __forceinline__ void epi_store_i8(const unsigned short* lds, unsigned* Y, int lb) {
  int tr = threadIdx.x >> 2, q = threadIdx.x & 3;
  int grow = lb * 64 + tr;
  if (grow >= N_NODESC) return;
#pragma unroll
  for (int i = 0; i < 8; ++i) {
    int col = (q + 4 * i) * 4;
    ushort4 v = *(const ushort4*)&lds[tr * 136 + col];
    unsigned pk = pk_i8x4(bf2f(v.x), bf2f(v.y), bf2f(v.z), bf2f(v.w));
    Y[(size_t)grow * 32 + q + 4 * i] = pk;
  }
}

// ---------------- GEMM layer1 (fp32 in): h(int8, x16) = (X @ W1) * inv * 16 ----------------
__global__ __launch_bounds__(256) void gemm_l1(const float* __restrict__ xA, const float* __restrict__ xB,
                                               const unsigned short* __restrict__ Wt, const float* __restrict__ inv,
                                               unsigned* __restrict__ H) {
  __shared__ unsigned short lds[64 * 136];
  int side = blockIdx.x / GG, lb = blockIdx.x % GG;
  const float* X = side ? xB : xA;
  const unsigned short* Wm = Wt + (size_t)(side * 2) * 128 * 512;
  const float* iv = inv + side * N_NODESC;
  unsigned* Y = H + (size_t)side * N_NODESC * 32;
  int wave = threadIdx.x >> 6, lane = threadIdx.x & 63;
  int l15 = lane & 15, kb = lane >> 4;
  int row0 = lb * 64 + wave * 16;
  int rA = row0 + l15;
  const bool valid = rA < N_NODESC;
  f32x4 acc[8];
#pragma unroll
  for (int nf = 0; nf < 8; ++nf) acc[nf] = 0.f;
#pragma unroll
  for (int ks = 0; ks < 4; ++ks) {
    int kbase = ks * 32 + kb * 8;
    bf16x8 a;
    if (valid) {
      const float* xp = &X[(size_t)rA * DIMC + kbase];
      float4 x0 = *(const float4*)xp;
      float4 x1 = *(const float4*)(xp + 4);
      a[0] = (short)f2bf(x0.x); a[1] = (short)f2bf(x0.y);
      a[2] = (short)f2bf(x0.z); a[3] = (short)f2bf(x0.w);
      a[4] = (short)f2bf(x1.x); a[5] = (short)f2bf(x1.y);
      a[6] = (short)f2bf(x1.z); a[7] = (short)f2bf(x1.w);
    } else {
      a = (short)0;
    }
    const unsigned short* wp = Wm + (size_t)(ks * 16) * 512 + lane * 8;
#pragma unroll
    for (int nf = 0; nf < 8; ++nf) {
      bf16x8 bh = *(const bf16x8*)(wp + (nf * 2) * 512);
      bf16x8 bl = *(const bf16x8*)(wp + (nf * 2 + 1) * 512);
      acc[nf] = __builtin_amdgcn_mfma_f32_16x16x32_bf16(a, bh, acc[nf], 0, 0, 0);
      acc[nf] = __builtin_amdgcn_mfma_f32_16x16x32_bf16(a, bl, acc[nf], 0, 0, 0);
    }
  }
  int lrow = wave * 16 + kb * 4;
#pragma unroll
  for (int r = 0; r < 4; ++r) {
    int rr = row0 + kb * 4 + r;
    float s = (rr < N_NODESC) ? iv[rr] * 16.0f : 0.f;  // x16 into int8 range
#pragma unroll
    for (int nf = 0; nf < 8; ++nf) {
      lds[(lrow + r) * 136 + nf * 16 + l15] = f2bf(acc[nf][r] * s);
    }
  }
  __syncthreads();
  epi_store_i8(lds, Y, lb);
}

// ---------------- GEMM layer2 (bf16 in): h(int8, x16) = (G @ W2) * inv * 16 ----------------
__global__ __launch_bounds__(256) void gemm_l2(const unsigned short* __restrict__ Gb,
                                               const unsigned short* __restrict__ Wt, const float* __restrict__ inv,
                                               unsigned* __restrict__ H) {
  __shared__ unsigned short lds[64 * 136];
  int side = blockIdx.x / GG, lb = blockIdx.x % GG;
  const unsigned short* X = Gb + (size_t)side * N_NODESC * DIMC;
  const unsigned short* Wm = Wt + (size_t)(side * 2 + 1) * 128 * 512;
  const float* iv = inv + side * N_NODESC;
  unsigned* Y = H + (size_t)side * N_NODESC * 32;
  int wave = threadIdx.x >> 6, lane = threadIdx.x & 63;
  int l15 = lane & 15, kb = lane >> 4;
  int row0 = lb * 64 + wave * 16;
  int rA = row0 + l15;
  const bool valid = rA < N_NODESC;
  f32x4 acc[8];
#pragma unroll
  for (int nf = 0; nf < 8; ++nf) acc[nf] = 0.f;
#pragma unroll
  for (int ks = 0; ks < 4; ++ks) {
    int kbase = ks * 32 + kb * 8;
    bf16x8 a;
    if (valid) {
      a = *(const bf16x8*)&X[(size_t)rA * DIMC + kbase];
    } else {
      a = (short)0;
    }
    const unsigned short* wp = Wm + (size_t)(ks * 16) * 512 + lane * 8;
#pragma unroll
    for (int nf = 0; nf < 8; ++nf) {
      bf16x8 bh = *(const bf16x8*)(wp + (nf * 2) * 512);
      bf16x8 bl = *(const bf16x8*)(wp + (nf * 2 + 1) * 512);
      acc[nf] = __builtin_amdgcn_mfma_f32_16x16x32_bf16(a, bh, acc[nf], 0, 0, 0);
      acc[nf] = __builtin_amdgcn_mfma_f32_16x16x32_bf16(a, bl, acc[nf], 0, 0, 0);
    }
  }
  int lrow = wave * 16 + kb * 4;
#pragma unroll
  for (int r = 0; r < 4; ++r) {
    int rr = row0 + kb * 4 + r;
    float s = (rr < N_NODESC) ? iv[rr] * 16.0f : 0.f;
#pragma unroll
    for (int nf = 0; nf < 8; ++nf) {
      lds[(lrow + r) * 136 + nf * 16 + l15] = f2bf(acc[nf][r] * s);
    }
  }
  __syncthreads();
  epi_store_i8(lds, Y, lb);
}

// ---------------- aggregation (both sides, int8 gather, biased 16-bit-field accumulate) ----------------
__global__ __launch_bounds__(256) void agg12(const unsigned* __restrict__ H, const float* __restrict__ inv,
                                             const int* __restrict__ rowptr, const unsigned short* __restrict__ csr16,
                                             const float* __restrict__ biasA, const float* __restrict__ biasB,
                                             unsigned short* __restrict__ G, int do_relu) {
  int side = blockIdx.x / AG, lb = blockIdx.x % AG;
  int node = lb * 4 + (threadIdx.x >> 6);
  if (node >= N_NODESC) return;
  const unsigned* Hp = H + (size_t)side * N_NODESC * 32;
  const float* iv = inv + side * N_NODESC;
  const int* rp = rowptr + side * (N_NODESC + 1);
  const unsigned short* csr = csr16 + (size_t)side * N_EDGESC;
  const float* bias = side ? biasB : biasA;
  unsigned short* out = G + (size_t)side * N_NODESC * DIMC;
  int lane = threadIdx.x & 63;
  int g16 = lane & 15;   // 16-lane group: 16 x 8B = 128B row
  int ug2 = g16 * 2;     // uint index base
  int slot = lane >> 4;  // 0..3: 4 edges per load instruction
  int beg = rp[node], end = rp[node + 1];
  unsigned acc[4];
#pragma unroll
  for (int j = 0; j < 4; ++j) acc[j] = 0u;
  int e = beg;
  for (; e + 16 <= end; e += 16) {  // 16 edges/iter, 4 gathers in flight per lane
    int s0 = csr[e + slot];
    int s1 = csr[e + 4 + slot];
    int s2 = csr[e + 8 + slot];
    int s3 = csr[e + 12 + slot];
    uint2 u0 = *(const uint2*)&Hp[(size_t)s0 * 32 + ug2];
    uint2 u1 = *(const uint2*)&Hp[(size_t)s1 * 32 + ug2];
    uint2 u2 = *(const uint2*)&Hp[(size_t)s2 * 32 + ug2];
    uint2 u3 = *(const uint2*)&Hp[(size_t)s3 * 32 + ug2];
    addu2_bias(acc, u0); addu2_bias(acc, u1); addu2_bias(acc, u2); addu2_bias(acc, u3);
  }
  for (int t2 = e + slot; t2 < end; t2 += 4) {
    uint2 u = *(const uint2*)&Hp[(size_t)csr[t2] * 32 + ug2];
    addu2_bias(acc, u);
  }
#pragma unroll
  for (int j = 0; j < 4; ++j) {
    acc[j] += __shfl_xor(acc[j], 16, 64);
    acc[j] += __shfl_xor(acc[j], 32, 64);
  }
  if (slot == 0) {
    uint2 su = *(const uint2*)&Hp[(size_t)node * 32 + ug2];
    addu2_bias(acc, su);  // self term
    int cnt = (end - beg) + 1;
    int bs = cnt << 7;  // 128 * cnt
    float sc = iv[node] * 0.0625f;  // undo x16
    float4 b0 = *(const float4*)&bias[g16 * 8];
    float4 b1 = *(const float4*)&bias[g16 * 8 + 4];
    // acc[0]:(d0,d2) acc[1]:(d1,d3) acc[2]:(d4,d6) acc[3]:(d5,d7)
    float o[8];
    o[0] = (float)((int)(acc[0] & 0xFFFFu) - bs) * sc + b0.x;
    o[1] = (float)((int)(acc[1] & 0xFFFFu) - bs) * sc + b0.y;
    o[2] = (float)((int)(acc[0] >> 16) - bs) * sc + b0.z;
    o[3] = (float)((int)(acc[1] >> 16) - bs) * sc + b0.w;
    o[4] = (float)((int)(acc[2] & 0xFFFFu) - bs) * sc + b1.x;
    o[5] = (float)((int)(acc[3] & 0xFFFFu) - bs) * sc + b1.y;
    o[6] = (float)((int)(acc[2] >> 16) - bs) * sc + b1.z;
    o[7] = (float)((int)(acc[3] >> 16) - bs) * sc + b1.w;
    if (do_relu) {
#pragma unroll
      for (int j = 0; j < 8; ++j) o[j] = (o[j] > 0.f) ? o[j] : SLOPEF * o[j];
    }
    uint4 w;
    w.x = (unsigned)f2bf(o[0]) | ((unsigned)f2bf(o[1]) << 16);
    w.y = (unsigned)f2bf(o[2]) | ((unsigned)f2bf(o[3]) << 16);
    w.z = (unsigned)f2bf(o[4]) | ((unsigned)f2bf(o[5]) << 16);
    w.w = (unsigned)f2bf(o[6]) | ((unsigned)f2bf(o[7]) << 16);
    *(uint4*)&out[(size_t)node * DIMC + g16 * 8] = w;
  }
}

// ---------------- pooling (both sides, bf16 in) ----------------
__global__ __launch_bounds__(128) void pool2(const unsigned short* __restrict__ G,
                                             const int* __restrict__ batA, const int* __restrict__ batB,
                                             float* __restrict__ psA, float* __restrict__ psB,
                                             int* __restrict__ pcA, int* __restrict__ pcB) {
  int side = blockIdx.x / GG, lb = blockIdx.x % GG;
  const unsigned short* g = G + (size_t)side * N_NODESC * DIMC;
  const int* batch = side ? batB : batA;
  float* psum = side ? psB : psA;
  int* pcnt = side ? pcB : pcA;
  int t = threadIdx.x;
  int n0 = lb * 64;
  int nend = min(n0 + 64, N_NODESC);
  int cur = batch[n0];
  float acc = 0.f;
  int c = 0;
  for (int n = n0; n < nend; ++n) {
    int b = batch[n];
    if (b != cur) {
      atomicAdd(&psum[cur * DIMC + t], acc);
      if (t == 0) atomicAdd(&pcnt[cur], c);
      acc = 0.f;
      c = 0;
      cur = b;
    }
    acc += bf2f(g[(size_t)n * DIMC + t]);
    c += 1;
  }
  atomicAdd(&psum[cur * DIMC + t], acc);
  if (t == 0) atomicAdd(&pcnt[cur], c);
}

// ---------------- fused mean + qkv ----------------
__global__ __launch_bounds__(128) void meanqkv(const float* __restrict__ psA, const int* __restrict__ pcA,
                                               const float* __restrict__ psB, const int* __restrict__ pcB,
                                               const float* __restrict__ Wq, const float* __restrict__ bq,
                                               const float* __restrict__ Wk, const float* __restrict__ bk,
                                               const float* __restrict__ Wv, const float* __restrict__ bv,
                                               float* __restrict__ mhA, float* __restrict__ mhB,
                                               float* __restrict__ Q0, float* __restrict__ K0, float* __restrict__ V0,
                                               float* __restrict__ Q1, float* __restrict__ K1, float* __restrict__ V1) {
  __shared__ float xs[DIMC];
  int task = blockIdx.x >> 6, r = blockIdx.x & 63, t = threadIdx.x;
  bool sideA = (task == 0 || task == 4 || task == 5);
  const float* ps = sideA ? psA : psB;
  const int* pc = sideA ? pcA : pcB;
  const float *W, *b;
  float* Y;
  switch (task) {
    case 0: W = Wq; b = bq; Y = Q0; break;
    case 1: W = Wk; b = bk; Y = K0; break;
    case 2: W = Wv; b = bv; Y = V0; break;
    case 3: W = Wq; b = bq; Y = Q1; break;
    case 4: W = Wk; b = bk; Y = K1; break;
    default: W = Wv; b = bv; Y = V1; break;
  }
  float xv = ps[r * DIMC + t] / (float)max(pc[r], 1);
  xs[t] = xv;
  if (task == 0) mhA[r * DIMC + t] = xv;
  if (task == 3) mhB[r * DIMC + t] = xv;
  __syncthreads();
  float acc = b[t];
  for (int k = 0; k < DIMC; ++k) acc += xs[k] * W[k * DIMC + t];
  Y[r * DIMC + t] = acc;
}

__global__ __launch_bounds__(64) void attn_kernel(const float* __restrict__ Q0, const float* __restrict__ K0,
                                                  const float* __restrict__ V0, const float* __restrict__ Q1,
                                                  const float* __restrict__ K1, const float* __restrict__ V1,
                                                  float* __restrict__ O0, float* __restrict__ O1) {
  __shared__ float ps[64];
  int b = blockIdx.x;
  int dir = b >> 8, h = (b >> 6) & 3, q = b & 63;
  const float* Q = dir ? Q1 : Q0;
  const float* K = dir ? K1 : K0;
  const float* V = dir ? V1 : V0;
  float* O = dir ? O1 : O0;
  int k = threadIdx.x;
  const float* qp = Q + q * DIMC + h * HDC;
  const float* kp = K + k * DIMC + h * HDC;
  float s = 0.f;
#pragma unroll
  for (int d = 0; d < HDC; ++d) s += qp[d] * kp[d];
  s *= SCALEF;
  float m = s;
#pragma unroll
  for (int off = 32; off >= 1; off >>= 1) m = fmaxf(m, __shfl_xor(m, off, 64));
  float p = __expf(s - m);
  float sum = p;
#pragma unroll
  for (int off = 32; off >= 1; off >>= 1) sum += __shfl_xor(sum, off, 64);
  p /= sum;
  ps[k] = p;
  __syncthreads();
  int half = k >> 5, d = k & 31;
  float acc = 0.f;
#pragma unroll
  for (int j = 0; j < 32; ++j) {
    int kk = half * 32 + j;
    acc += ps[kk] * V[kk * DIMC + h * HDC + d];
  }
  acc += __shfl_xor(acc, 32, 64);
  if (half == 0) O[q * DIMC + h * HDC + d] = acc;
}

__device__ inline float blk_sum128(float v, float* red) {
#pragma unroll
  for (int off = 32; off >= 1; off >>= 1) v += __shfl_xor(v, off, 64);
  if ((threadIdx.x & 63) == 0) red[threadIdx.x >> 6] = v;
  __syncthreads();
  float r = red[0] + red[1];
  __syncthreads();
  return r;
}

// ---------------- fused oln + ff1 (256 thr: LN on t<128, FF1 on all) ----------------
__global__ __launch_bounds__(256) void olnff1(const float* __restrict__ O0, const float* __restrict__ O1,
                                              const float* __restrict__ mhA, const float* __restrict__ mhB,
                                              const float* __restrict__ Wo, const float* __restrict__ bo,
                                              const float* __restrict__ g1, const float* __restrict__ be1,
                                              const float* __restrict__ Wf1, const float* __restrict__ bf1,
                                              float* __restrict__ X0, float* __restrict__ X1,
                                              float* __restrict__ F0, float* __restrict__ F1) {
  __shared__ float os[DIMC];
  __shared__ float xs[DIMC];
  __shared__ float red4[4];
  int dir = blockIdx.x >> 6, q = blockIdx.x & 63, t = threadIdx.x;
  const float* O = dir ? O1 : O0;
  const float* xq = dir ? mhB : mhA;
  float* Xo = dir ? X1 : X0;
  float* F = dir ? F1 : F0;
  if (t < DIMC) os[t] = O[q * DIMC + t];
  __syncthreads();
  bool act = t < DIMC;
  float acc = 0.f;
  if (act) {
    acc = bo[t] + xq[q * DIMC + t];
    for (int k = 0; k < DIMC; ++k) acc += os[k] * Wo[k * DIMC + t];
  }
  float v = act ? acc : 0.f;
#pragma unroll
  for (int off = 32; off >= 1; off >>= 1) v += __shfl_xor(v, off, 64);
  if ((t & 63) == 0) red4[t >> 6] = v;
  __syncthreads();
  float mean = (red4[0] + red4[1] + red4[2] + red4[3]) * (1.f / DIMC);
  __syncthreads();
  float d = act ? (acc - mean) : 0.f;
  float v2 = d * d;
#pragma unroll
  for (int off = 32; off >= 1; off >>= 1) v2 += __shfl_xor(v2, off, 64);
  if ((t & 63) == 0) red4[t >> 6] = v2;
  __syncthreads();
  float var = (red4[0] + red4[1] + red4[2] + red4[3]) * (1.f / DIMC);
  if (act) {
    float xv = d * rsqrtf(var + EPSF) * g1[t] + be1[t];
    xs[t] = xv;
    Xo[q * DIMC + t] = xv;
  }
  __syncthreads();
  float facc = bf1[t];
  for (int k = 0; k < DIMC; ++k) facc += xs[k] * Wf1[k * 256 + t];
  facc = (facc > 0.f) ? facc : SLOPEF * facc;
  F[q * 256 + t] = facc;
}

// ---------------- fused ffln (both dirs) + head ----------------
__global__ __launch_bounds__(128) void fflnhead(const float* __restrict__ F0, const float* __restrict__ F1,
                                                const float* __restrict__ X0, const float* __restrict__ X1,
                                                const float* __restrict__ Wf2, const float* __restrict__ bf2,
                                                const float* __restrict__ g2, const float* __restrict__ be2,
                                                const float* __restrict__ Wl1, const float* __restrict__ bl1,
                                                const float* __restrict__ Wl2, const float* __restrict__ bl2,
                                                float* __restrict__ out) {
  __shared__ float fs[256];
  __shared__ float cs[256];
  __shared__ float red[2];
  int g = blockIdx.x, t = threadIdx.x;
  for (int dir = 0; dir < 2; ++dir) {
    const float* F = dir ? F1 : F0;
    const float* X = dir ? X1 : X0;
    fs[t] = F[g * 256 + t];
    fs[t + 128] = F[g * 256 + t + 128];
    __syncthreads();
    float acc = bf2[t] + X[g * DIMC + t];
    for (int k = 0; k < 256; ++k) acc += fs[k] * Wf2[k * DIMC + t];
    float mean = blk_sum128(acc, red) * (1.f / DIMC);
    float d = acc - mean;
    float var = blk_sum128(d * d, red) * (1.f / DIMC);
    cs[dir * DIMC + t] = d * rsqrtf(var + EPSF) * g2[t] + be2[t];
    __syncthreads();
  }
  float acc = bl1[t];
  for (int k = 0; k < 256; ++k) acc += cs[k] * Wl1[k * DIMC + t];
  acc = fmaxf(acc, 0.f);
  float s = blk_sum128(acc * Wl2[t], red);
  if (t == 0) out[g] = s + bl2[0];
}

// ---------------- host ----------------
extern "C" void kernel_launch(void* const* d_in, const int* in_sizes, int n_in,
                              void* d_out, int out_size, void* d_ws, size_t ws_size,
                              hipStream_t stream) {
  const float* xA = (const float*)d_in[0];
  const float* xB = (const float*)d_in[1];
  const int* eiA = (const int*)d_in[2];
  const int* eiB = (const int*)d_in[3];
  const int* batA = (const int*)d_in[4];
  const int* batB = (const int*)d_in[5];
  const float* WA1 = (const float*)d_in[6];
  const float* WA2 = (const float*)d_in[7];
  const float* WB1 = (const float*)d_in[8];
  const float* WB2 = (const float*)d_in[9];
  const float* Wq = (const float*)d_in[10];
  const float* Wk = (const float*)d_in[11];
  const float* Wv = (const float*)d_in[12];
  const float* Wo = (const float*)d_in[13];
  const float* Wf1 = (const float*)d_in[14];
  const float* Wf2 = (const float*)d_in[15];
  const float* Wl1 = (const float*)d_in[16];
  const float* Wl2 = (const float*)d_in[17];
  const float* bA1 = (const float*)d_in[18];
  const float* bA2 = (const float*)d_in[19];
  const float* bB1 = (const float*)d_in[20];
  const float* bB2 = (const float*)d_in[21];
  const float* bq = (const float*)d_in[22];
  const float* bk = (const float*)d_in[23];
  const float* bv = (const float*)d_in[24];
  const float* bo = (const float*)d_in[25];
  const float* bf1 = (const float*)d_in[26];
  const float* bf2 = (const float*)d_in[27];
  const float* bl1 = (const float*)d_in[28];
  const float* bl2 = (const float*)d_in[29];
  const float* g1 = (const float*)d_in[30];
  const float* be1 = (const float*)d_in[31];
  const float* g2 = (const float*)d_in[32];
  const float* be2 = (const float*)d_in[33];

  char* base = (char*)d_ws;
  size_t off = 0;
  auto alloc = [&](size_t bytes) -> char* {
    char* r = base + off;
    off += (bytes + 255) & ~(size_t)255;
    return r;
  };
  unsigned* h_buf = (unsigned*)alloc((size_t)2 * N_NODESC * 32 * 4);                // int8 x16, both sides
  unsigned short* g_buf = (unsigned short*)alloc((size_t)2 * N_NODESC * DIMC * 2);  // bf16, both sides
  unsigned* packed = (unsigned*)alloc((size_t)2 * N_EDGESC * 4);
  unsigned short* csr16 = (unsigned short*)alloc((size_t)2 * N_EDGESC * 2);
  int* rowptr = (int*)alloc((size_t)2 * (N_NODESC + 1) * 4);
  float* inv = (float*)alloc((size_t)2 * N_NODESC * 4);
  int* hist = (int*)alloc((size_t)2 * KBLK * NBUK * 4);
  int* bbase = (int*)alloc((size_t)2 * KBLK * NBUK * 4);
  int* bucket_base = (int*)alloc((size_t)2 * (NBUK + 1) * 4);
  unsigned short* wtbuf = (unsigned short*)alloc((size_t)4 * 128 * 512 * 2);
  size_t poff0 = off;
  float* psA = (float*)alloc(NGC * DIMC * 4);
  float* psB = (float*)alloc(NGC * DIMC * 4);
  int* pcA = (int*)alloc(NGC * 4);
  int* pcB = (int*)alloc(NGC * 4);
  size_t pbytes = off - poff0;
  float* mhA = (float*)alloc(NGC * DIMC * 4);
  float* mhB = (float*)alloc(NGC * DIMC * 4);
  float* Q0 = (float*)alloc(NGC * DIMC * 4);
  float* K0 = (float*)alloc(NGC * DIMC * 4);
  float* V0 = (float*)alloc(NGC * DIMC * 4);
  float* Q1 = (float*)alloc(NGC * DIMC * 4);
  float* K1 = (float*)alloc(NGC * DIMC * 4);
  float* V1 = (float*)alloc(NGC * DIMC * 4);
  float* O0 = (float*)alloc(NGC * DIMC * 4);
  float* O1 = (float*)alloc(NGC * DIMC * 4);
  float* X0 = (float*)alloc(NGC * DIMC * 4);
  float* X1 = (float*)alloc(NGC * DIMC * 4);
  float* F0 = (float*)alloc(NGC * 256 * 4);
  float* F1 = (float*)alloc(NGC * 256 * 4);

  hipMemsetAsync(base + poff0, 0, pbytes, stream);
  wconv<<<64, 256, 0, stream>>>(WA1, WA2, WB1, WB2, wtbuf);

  kbhist2<<<2 * KBLK, 1024, 0, stream>>>(eiA, eiB, hist);
  kbscan2<<<2, 1024, 0, stream>>>(hist, bbase, bucket_base);
  kbin2<<<2 * KBLK, 1024, 0, stream>>>(eiA, eiB, bbase, packed);
  kcsr2<<<2 * NBUK, 256, 0, stream>>>(packed, bucket_base, csr16, rowptr, inv);

  gemm_l1<<<2 * GG, 256, 0, stream>>>(xA, xB, wtbuf, inv, h_buf);
  agg12<<<2 * AG, 256, 0, stream>>>(h_buf, inv, rowptr, csr16, bA1, bB1, g_buf, 1);
  gemm_l2<<<2 * GG, 256, 0, stream>>>(g_buf, wtbuf, inv, h_buf);
  agg12<<<2 * AG, 256, 0, stream>>>(h_buf, inv, rowptr, csr16, bA2, bB2, g_buf, 0);
  pool2<<<2 * GG, 128, 0, stream>>>(g_buf, batA, batB, psA, psB, pcA, pcB);

  meanqkv<<<384, 128, 0, stream>>>(psA, pcA, psB, pcB, Wq, bq, Wk, bk, Wv, bv,
                                   mhA, mhB, Q0, K0, V0, Q1, K1, V1);
  attn_kernel<<<512, 64, 0, stream>>>(Q0, K0, V0, Q1, K1, V1, O0, O1);
  olnff1<<<128, 256, 0, stream>>>(O0, O1, mhA, mhB, Wo, bo, g1, be1, Wf1, bf1, X0, X1, F0, F1);
  fflnhead<<<64, 128, 0, stream>>>(F0, F1, X0, X1, Wf2, bf2, g2, be2, Wl1, bl1, Wl2, bl2, (float*)d_out);
}